// Round 7
// baseline (229.694 us; speedup 1.0000x reference)
//
#include <hip/hip_runtime.h>
#include <hip/hip_bf16.h>

typedef unsigned short u16;
typedef __bf16 bf16x8 __attribute__((ext_vector_type(8)));
typedef float floatx4 __attribute__((ext_vector_type(4)));
typedef unsigned short ushort8 __attribute__((ext_vector_type(8)));

#define GLOBAL_AS(p) ((const __attribute__((address_space(1))) void*)(p))
#define LDS_AS(p) ((__attribute__((address_space(3))) void*)(p))

constexpr int NB = 8192;
constexpr int DIN = 512;
constexpr int DH = 2048;
constexpr int DOUT = 512;
constexpr int NEXP = 8;
constexpr int ROWCAP = NB + NEXP * 128;    // 128-padded segments (write-side bound)
constexpr int RCAPRD = NB + NEXP * 256;    // read-side row capacity (256-tile overread pad)
constexpr int TILE = 8192;                 // elements in a 128x64 bf16 tile

__device__ __forceinline__ u16 f2bf(float f) {
    unsigned u = __builtin_bit_cast(unsigned, f);
    unsigned r = u + 0x7FFFu + ((u >> 16) & 1u);
    return (u16)(r >> 16);
}

// element offset within a 128x64 tile for (row, klocal), xor-swizzled 16B chunks
__device__ __forceinline__ int slot_off(int row, int kl) {
    return row * 64 + ((((kl >> 3) ^ (row & 7)) << 3) | (kl & 7));
}

// ---------------- routing: one single-block kernel, per-wave sub-counters ----------------
__global__ void route_kernel(const int* __restrict__ groups, int* __restrict__ cnt,
                             int* __restrict__ offs, int* __restrict__ perm,
                             int* __restrict__ rpos) {
    __shared__ int wc[NEXP * 4];    // [e][wave] counts
    __shared__ int lcur[NEXP * 4];  // running positions
    int t = threadIdx.x;
    int w = t >> 6;
    if (t < NEXP * 4) wc[t] = 0;
    __syncthreads();
    for (int i = t; i < NB; i += 256) atomicAdd(&wc[groups[i] * 4 + w], 1);
    __syncthreads();
    if (t == 0) {
        int run = 0;
        for (int e = 0; e < NEXP; ++e) {
            offs[e] = run;
            int s = run;
            for (int j = 0; j < 4; ++j) { lcur[e * 4 + j] = s; s += wc[e * 4 + j]; }
            cnt[e] = s - run;
            run += (((s - run) + 127) >> 7) << 7;   // 128-aligned segments
        }
    }
    __syncthreads();
    for (int i = t; i < NB; i += 256) {
        int e = groups[i];
        int pos = atomicAdd(&lcur[e * 4 + w], 1);
        perm[pos] = i;
        rpos[i] = pos;
    }
}

// ---------------- fused wide prep: W1/W2 transpose+tile | gather-x ----------------
// grid.x = 4096 (weights) + 2048 (gather) = 6144
__global__ __launch_bounds__(256) void prep_kernel(
        const float* __restrict__ x, const float* __restrict__ W1,
        const float* __restrict__ W2, const int* __restrict__ rpos,
        u16* __restrict__ xsT, u16* __restrict__ w1tT, u16* __restrict__ w2tT) {
    int bx = blockIdx.x;
    int t = threadIdx.x;
    if (bx < 4096) {
        // weight transpose+convert+tile: src [E][K][N] -> tiled [e][nt][kt][128][64]
        __shared__ float tile[64][65];
        bool isW1 = bx < 2048;
        int b = isW1 ? bx : bx - 2048;
        int e = b >> 8;
        int q = b & 255;
        int C = isW1 ? DH : DOUT;                 // N-dim
        int NTP = C >> 7;                         // n-tiles (16 / 4)
        int KTP = isW1 ? (DIN >> 6) : (DH >> 6);  // k-tiles (8 / 32)
        int rt = isW1 ? (q >> 5) : (q >> 3);      // k 64-tile idx
        int ct = isW1 ? (q & 31) : (q & 7);       // n 64-tile idx
        const float* s = (isW1 ? W1 : W2) + (size_t)e * (isW1 ? DIN * DH : DH * DOUT);
        u16* d = isW1 ? w1tT : w2tT;
        int r0 = rt * 64, c0 = ct * 64;
        for (int i = 0; i < 4; ++i) {
            int r = (t >> 4) + i * 16;
            int c = (t & 15) * 4;
            const float4 v = *(const float4*)&s[(size_t)(r0 + r) * C + c0 + c];
            tile[r][c] = v.x; tile[r][c + 1] = v.y; tile[r][c + 2] = v.z; tile[r][c + 3] = v.w;
        }
        __syncthreads();
        for (int i = 0; i < 4; ++i) {
            int c = (t >> 4) + i * 16;    // n-local
            int r = (t & 15) * 4;         // k-local, 4 consecutive
            int n = c0 + c, k = r0 + r;
            ushort4 o;
            o.x = f2bf(tile[r][c]); o.y = f2bf(tile[r + 1][c]);
            o.z = f2bf(tile[r + 2][c]); o.w = f2bf(tile[r + 3][c]);
            size_t off = ((size_t)(e * NTP + (n >> 7)) * KTP + (k >> 6)) * TILE
                         + slot_off(n & 127, k & 63);
            *(ushort4*)&d[off] = o;
        }
    } else {
        // gather-x: 4 rows per block, 64 lanes per row, 8 elems/lane
        int r = t >> 6, lane = t & 63;
        int i = (bx - 4096) * 4 + r;
        int pos = rpos[i];
        int k = lane * 8;
        const float4 a = *(const float4*)&x[(size_t)i * DIN + k];
        const float4 b = *(const float4*)&x[(size_t)i * DIN + k + 4];
        ushort8 o;
        o[0] = f2bf(a.x); o[1] = f2bf(a.y); o[2] = f2bf(a.z); o[3] = f2bf(a.w);
        o[4] = f2bf(b.x); o[5] = f2bf(b.y); o[6] = f2bf(b.z); o[7] = f2bf(b.w);
        int lp = pos & 127;
        size_t off = (size_t)(pos >> 7) * 8 * TILE + (size_t)(k >> 6) * TILE
                     + slot_off(lp, k & 63);
        *(ushort8*)&xsT[off] = o;
    }
}

// ---------------- 256x128-tile GEMM building blocks, 512-thread / 8-wave ----------------
// VGPR discipline (rounds 2-6): allocator budget defaults to 131072/(2*threads)
// = 128 for 512-thread blocks; acc[4][4] (64) + frags + addressing fits (r6
// measured 96). Per K-step LDS image: 3 slots {A0 rows 0-127, A1 rows 128-255,
// B n 0-127}, each a 128x64 pre-swizzled tile (16 KB).
// TRIPLE-buffered (3 x 48 KB = 144 KiB): counted-vmcnt pipeline (T4) -- at
// iter kt we issue stage(kt+2) then s_waitcnt vmcnt(12), which waits only for
// stage(kt)'s 6 loads, issued TWO compute phases earlier -> zero steady-state
// latency exposure. Round-6's __syncthreads drained the just-issued prefetch
// every step (the m233 stage+vmcnt+barrier critical path: MfmaUtil 13.7%).
// Safety: stage(kt+2) overwrites the buffer consumed at iter kt-1 (all waves
// passed that iter's end barrier); each wave waits its OWN vmcnt then
// barriers (m201 pattern); sched_barrier(0) pins ds_reads below the wait.

#define LDF(base, row, c0) \
    (*(const bf16x8*)&(base)[(row) * 64 + ((((c0) ^ ((row) & 7))) << 3)])

// 512 threads x 16B = 8KB per gload round; 2 rounds per 16KB slot, 6 total
__device__ __forceinline__ void stage3(const u16* a0, const u16* a1, const u16* b,
                                       u16* buf, int soff, int doff) {
    __builtin_amdgcn_global_load_lds(GLOBAL_AS(a0 + soff), LDS_AS(buf + doff), 16, 0, 0);
    __builtin_amdgcn_global_load_lds(GLOBAL_AS(a0 + 4096 + soff), LDS_AS(buf + 4096 + doff), 16, 0, 0);
    __builtin_amdgcn_global_load_lds(GLOBAL_AS(a1 + soff), LDS_AS(buf + TILE + doff), 16, 0, 0);
    __builtin_amdgcn_global_load_lds(GLOBAL_AS(a1 + 4096 + soff), LDS_AS(buf + TILE + 4096 + doff), 16, 0, 0);
    __builtin_amdgcn_global_load_lds(GLOBAL_AS(b + soff), LDS_AS(buf + 2 * TILE + doff), 16, 0, 0);
    __builtin_amdgcn_global_load_lds(GLOBAL_AS(b + 4096 + soff), LDS_AS(buf + 2 * TILE + 4096 + doff), 16, 0, 0);
}

__device__ __forceinline__ void compute_step(const u16* At, const u16* Bt,
                                             int arow, int brow,
                                             floatx4 (&acc)[4][4], int q, int li) {
#pragma unroll
    for (int s = 0; s < 2; ++s) {
        int c0 = s * 4 + q;
        bf16x8 bfr[4];
#pragma unroll
        for (int fn = 0; fn < 4; ++fn) bfr[fn] = LDF(Bt, brow + fn * 16 + li, c0);
#pragma unroll
        for (int fm = 0; fm < 4; ++fm) {
            bf16x8 af = LDF(At, arow + fm * 16 + li, c0);
#pragma unroll
            for (int fn = 0; fn < 4; ++fn)
                acc[fm][fn] = __builtin_amdgcn_mfma_f32_16x16x32_bf16(
                    af, bfr[fn], acc[fm][fn], 0, 0, 0);
        }
    }
}

// counted-vmcnt triple-buffer K-loop (T4). sm = 9 slots (3 bufs x 3 slots).
template <int KT>
__device__ __forceinline__ void gemm_core3(const u16* a0, const u16* a1, const u16* b0,
                                           u16* sm, floatx4 (&acc)[4][4],
                                           int aslot, int arow, int brow,
                                           int q, int li, int soff, int doff) {
    stage3(a0, a1, b0, sm, soff, doff);                              // kt=0 -> buf0
    stage3(a0 + TILE, a1 + TILE, b0 + TILE, sm + 3 * TILE, soff, doff);  // kt=1 -> buf1
    int cur = 0;   // buffer index holding K-tile kt
#pragma unroll 1
    for (int kt = 0; kt < KT; ++kt) {
        if (kt + 2 < KT) {
            int nb = cur + 2; if (nb >= 3) nb -= 3;   // (kt+2)%3: held kt-1, dead since iter kt-1
            stage3(a0 + (size_t)(kt + 2) * TILE, a1 + (size_t)(kt + 2) * TILE,
                   b0 + (size_t)(kt + 2) * TILE, sm + (size_t)nb * 3 * TILE, soff, doff);
            asm volatile("s_waitcnt vmcnt(12)" ::: "memory");   // kt's 6 done; kt+1,kt+2 fly
        } else if (kt + 1 < KT) {
            asm volatile("s_waitcnt vmcnt(6)" ::: "memory");    // kt's done; kt+1 flies
        } else {
            asm volatile("s_waitcnt vmcnt(0)" ::: "memory");    // final drain
        }
        __builtin_amdgcn_s_barrier();
        __builtin_amdgcn_sched_barrier(0);   // pin ds_reads below the data-ready point
        const u16* At = sm + (size_t)(cur * 3 + aslot) * TILE;
        const u16* Bt = sm + (size_t)(cur * 3 + 2) * TILE;
        compute_step(At, Bt, arow, brow, acc, q, li);
        __builtin_amdgcn_s_barrier();        // WAR: all waves done reading buf[cur-? ] regions
        cur = (cur == 2) ? 0 : cur + 1;
    }
}

// ---------------- pass A: h = relu(x @ W1 + b1), bf16 tiled out ----------------
// block tile 256m x 128n; grid = 8 experts x 16 n128-tiles x 4 m-slots = 512 (2/CU exact)
__global__ __launch_bounds__(512) __attribute__((amdgpu_waves_per_eu(2)))
void gemm_a(const u16* __restrict__ At, const u16* __restrict__ Bt,
            const float* __restrict__ bias, u16* __restrict__ hsT,
            const int* __restrict__ cnt, const int* __restrict__ offs) {
    __shared__ u16 sm[3 * 3 * TILE];   // 144 KiB
    int bx = blockIdx.x;
    int e = bx & 7;
    int r = bx >> 3;
    int nt = r & 15;
    int mt0 = r >> 4;
    int count = cnt[e];
    int base128 = offs[e] >> 7;
    int tid = threadIdx.x;
    int w = tid >> 6, l = tid & 63, q = l >> 4, li = l & 15;
    int wm = w >> 1, wn = w & 1;
    int aslot = wm >> 1, arow = (wm & 1) * 64, brow = wn * 64;
    int soff = tid * 8, doff = w * 512;
#pragma unroll 1
    for (int mt = mt0; mt * 256 < count; mt += 4) {
        const u16* a0 = At + (size_t)((base128 + mt * 2 + 0) * 8) * TILE;
        const u16* a1 = At + (size_t)((base128 + mt * 2 + 1) * 8) * TILE;
        const u16* b0 = Bt + (size_t)((e * 16 + nt) * 8) * TILE;
        floatx4 acc[4][4];
#pragma unroll
        for (int a = 0; a < 4; ++a)
#pragma unroll
            for (int b = 0; b < 4; ++b) acc[a][b] = (floatx4)0.0f;

        gemm_core3<8>(a0, a1, b0, sm, acc, aslot, arow, brow, q, li, soff, doff);

        // epilogue: wave owns 64x64; swizzled image in private 8 KB LDS region,
        // then fully-contiguous dump (lane-16B reads, conflict-free)
        float bv[4];
#pragma unroll
        for (int fn = 0; fn < 4; ++fn)
            bv[fn] = bias[(size_t)e * DH + nt * 128 + wn * 64 + fn * 16 + li];
        u16* img = sm + (size_t)w * 4096;
#pragma unroll
        for (int fm = 0; fm < 4; ++fm)
#pragma unroll
            for (int fn = 0; fn < 4; ++fn)
#pragma unroll
                for (int rr = 0; rr < 4; ++rr) {
                    float v = acc[fm][fn][rr] + bv[fn];
                    v = v > 0.0f ? v : 0.0f;
                    int row = fm * 16 + q * 4 + rr;   // 0..63 (wave-local m)
                    int col = fn * 16 + li;           // 0..63 (k-local in hsT tile)
                    img[row * 64 + ((((col >> 3) ^ (row & 7)) << 3) | (col & 7))] = f2bf(v);
                }
        // own-region write->read within one wave: in-order DS + compiler lgkmcnt
        if ((mt * 2 + aslot) * 128 < count) {   // guard vs expert segment end
            u16* dst = hsT + ((size_t)(base128 + mt * 2 + aslot) * 32 + nt * 2 + wn) * TILE
                       + (wm & 1) * 4096;
#pragma unroll
            for (int j = 0; j < 8; ++j)
                *(ushort8*)&dst[j * 512 + l * 8] = *(const ushort8*)&img[j * 512 + l * 8];
        }
        __syncthreads();   // img regions reused as staging buffers next m-iter
    }
}

// ---------------- pass B: partial[ks] = h @ W2 over K-half, fp32 sorted layout ----------
// block tile 256m x 128n; grid = 8 experts x 4 n128 x 2 ks x 4 m-slots = 256 (1/CU exact)
__global__ __launch_bounds__(512) __attribute__((amdgpu_waves_per_eu(2)))
void gemm_b(const u16* __restrict__ At, const u16* __restrict__ Bt,
            float* __restrict__ ps, const int* __restrict__ cnt,
            const int* __restrict__ offs) {
    __shared__ u16 sm[3 * 3 * TILE];   // 144 KiB
    int bx = blockIdx.x;
    int e = bx & 7;
    int r = bx >> 3;
    int nt = r & 3;
    int ks = (r >> 2) & 1;
    int mt0 = r >> 3;
    int count = cnt[e];
    int seg = offs[e];
    int base128 = seg >> 7;
    int tid = threadIdx.x;
    int w = tid >> 6, l = tid & 63, q = l >> 4, li = l & 15;
    int wm = w >> 1, wn = w & 1;
    int aslot = wm >> 1, arow = (wm & 1) * 64, brow = wn * 64;
    int soff = tid * 8, doff = w * 512;
#pragma unroll 1
    for (int mt = mt0; mt * 256 < count; mt += 4) {
        const u16* a0 = At + (size_t)((base128 + mt * 2 + 0) * 32 + ks * 16) * TILE;
        const u16* a1 = At + (size_t)((base128 + mt * 2 + 1) * 32 + ks * 16) * TILE;
        const u16* b0 = Bt + (size_t)((e * 4 + nt) * 32 + ks * 16) * TILE;
        floatx4 acc[4][4];
#pragma unroll
        for (int a = 0; a < 4; ++a)
#pragma unroll
            for (int b = 0; b < 4; ++b) acc[a][b] = (floatx4)0.0f;

        gemm_core3<16>(a0, a1, b0, sm, acc, aslot, arow, brow, q, li, soff, doff);

        // direct fp32 stores; guard per 128-row half against segment overflow
        if ((mt * 2 + aslot) * 128 < count) {
            float* pbase = ps + ((size_t)ks * ROWCAP + seg + (size_t)mt * 256) * DOUT;
#pragma unroll
            for (int fn = 0; fn < 4; ++fn) {
                int col = nt * 128 + wn * 64 + fn * 16 + li;
#pragma unroll
                for (int fm = 0; fm < 4; ++fm) {
                    int row0 = wm * 64 + fm * 16 + q * 4;
#pragma unroll
                    for (int rr = 0; rr < 4; ++rr)
                        pbase[(size_t)(row0 + rr) * DOUT + col] = acc[fm][fn][rr];
                }
            }
        }
        __syncthreads();   // LDS reuse across m-iterations
    }
}

// ---------------- reduce: out[i] = ps[0][rpos[i]] + ps[1][rpos[i]] + b2[groups[i]] ------
__global__ __launch_bounds__(256) void reduce_b(
        const float* __restrict__ ps, const int* __restrict__ rpos,
        const int* __restrict__ groups, const float* __restrict__ b2,
        float* __restrict__ out) {
    int idx = blockIdx.x * 256 + threadIdx.x;
    int i = idx >> 7;
    int c = (idx & 127) * 4;
    int pos = rpos[i];
    int g = groups[i];
    const float4 v0 = *(const float4*)&ps[(size_t)pos * DOUT + c];
    const float4 v1 = *(const float4*)&ps[((size_t)ROWCAP + pos) * DOUT + c];
    const float4 bb = *(const float4*)&b2[(size_t)g * DOUT + c];
    float4 o;
    o.x = v0.x + v1.x + bb.x; o.y = v0.y + v1.y + bb.y;
    o.z = v0.z + v1.z + bb.z; o.w = v0.w + v1.w + bb.w;
    *(float4*)&out[(size_t)i * DOUT + c] = o;
}

// ---------------- launch ----------------
extern "C" void kernel_launch(void* const* d_in, const int* in_sizes, int n_in,
                              void* d_out, int out_size, void* d_ws, size_t ws_size,
                              hipStream_t stream) {
    const float* x = (const float*)d_in[0];
    const int* groups = (const int*)d_in[1];
    const float* W1 = (const float*)d_in[2];
    const float* b1 = (const float*)d_in[3];
    const float* W2 = (const float*)d_in[4];
    const float* b2 = (const float*)d_in[5];
    float* out = (float*)d_out;

    char* ws = (char*)d_ws;
    size_t o = 0;
    auto alloc = [&](size_t bytes) {
        void* p = ws + o;
        o = (o + bytes + 255) & ~(size_t)255;
        return p;
    };
    int* cnt = (int*)alloc(NEXP * 4);
    int* offs = (int*)alloc(NEXP * 4);
    int* perm = (int*)alloc((size_t)ROWCAP * 4);
    int* rpos = (int*)alloc((size_t)NB * 4);
    u16* xsT = (u16*)alloc((size_t)(RCAPRD / 128) * 8 * TILE * 2);    // ~10.5 MB (read-pad)
    u16* w1tT = (u16*)alloc((size_t)NEXP * DIN * DH * 2);             // 16.8 MB
    u16* w2tT = (u16*)alloc((size_t)NEXP * DH * DOUT * 2);            // 16.8 MB
    u16* hsT = (u16*)alloc((size_t)(RCAPRD / 128) * 32 * TILE * 2);   // ~41.9 MB (read-pad)
    float* ps = (float*)alloc((size_t)2 * ROWCAP * DOUT * 4);         // ~37.7 MB

    route_kernel<<<1, 256, 0, stream>>>(groups, cnt, offs, perm, rpos);
    prep_kernel<<<6144, 256, 0, stream>>>(x, W1, W2, rpos, xsT, w1tT, w2tT);
    gemm_a<<<NEXP * 16 * 4, 512, 0, stream>>>(xsT, w1tT, b1, hsT, cnt, offs);
    gemm_b<<<NEXP * 4 * 2 * 4, 512, 0, stream>>>(hsT, w2tT, ps, cnt, offs);
    reduce_b<<<(NB * (DOUT / 4)) / 256, 256, 0, stream>>>(ps, rpos, groups, b2, out);
}

// Round 8
// 220.107 us; speedup vs baseline: 1.0436x; 1.0436x over previous
//
#include <hip/hip_runtime.h>
#include <hip/hip_bf16.h>

typedef unsigned short u16;
typedef __bf16 bf16x8 __attribute__((ext_vector_type(8)));
typedef float floatx4 __attribute__((ext_vector_type(4)));
typedef unsigned short ushort8 __attribute__((ext_vector_type(8)));

#define GLOBAL_AS(p) ((const __attribute__((address_space(1))) void*)(p))
#define LDS_AS(p) ((__attribute__((address_space(3))) void*)(p))

constexpr int NB = 8192;
constexpr int DIN = 512;
constexpr int DH = 2048;
constexpr int DOUT = 512;
constexpr int NEXP = 8;
constexpr int ROWCAP = NB + NEXP * 128;    // 128-padded segments (write-side bound)
constexpr int RCAPRD = NB + NEXP * 256;    // read-side row capacity (256-tile overread pad)
constexpr int TILE = 8192;                 // elements in a 128x64 bf16 tile

__device__ __forceinline__ u16 f2bf(float f) {
    unsigned u = __builtin_bit_cast(unsigned, f);
    unsigned r = u + 0x7FFFu + ((u >> 16) & 1u);
    return (u16)(r >> 16);
}

// element offset within a 128x64 tile for (row, klocal), xor-swizzled 16B chunks
__device__ __forceinline__ int slot_off(int row, int kl) {
    return row * 64 + ((((kl >> 3) ^ (row & 7)) << 3) | (kl & 7));
}

// ---------------- routing: one single-block kernel, 1024 threads / 16 waves ----------------
// (round-7 est ~15us at 256 thr: 1 CU x 32 serialized strides; 1024 thr -> 8 strides)
__global__ __launch_bounds__(1024) void route_kernel(
        const int* __restrict__ groups, int* __restrict__ cnt,
        int* __restrict__ offs, int* __restrict__ perm, int* __restrict__ rpos) {
    __shared__ int wc[NEXP * 16];    // [e][wave] counts
    __shared__ int lcur[NEXP * 16];  // running positions
    int t = threadIdx.x;
    int w = t >> 6;
    if (t < NEXP * 16) wc[t] = 0;
    __syncthreads();
    for (int i = t; i < NB; i += 1024) atomicAdd(&wc[groups[i] * 16 + w], 1);
    __syncthreads();
    if (t == 0) {
        int run = 0;
        for (int e = 0; e < NEXP; ++e) {
            offs[e] = run;
            int s = run;
            for (int j = 0; j < 16; ++j) { lcur[e * 16 + j] = s; s += wc[e * 16 + j]; }
            cnt[e] = s - run;
            run += (((s - run) + 127) >> 7) << 7;   // 128-aligned segments
        }
    }
    __syncthreads();
    for (int i = t; i < NB; i += 1024) {
        int e = groups[i];
        int pos = atomicAdd(&lcur[e * 16 + w], 1);
        perm[pos] = i;
        rpos[i] = pos;
    }
}

// ---------------- fused wide prep: W1/W2 transpose+tile | gather-x ----------------
// grid.x = 4096 (weights) + 2048 (gather) = 6144
__global__ __launch_bounds__(256) void prep_kernel(
        const float* __restrict__ x, const float* __restrict__ W1,
        const float* __restrict__ W2, const int* __restrict__ rpos,
        u16* __restrict__ xsT, u16* __restrict__ w1tT, u16* __restrict__ w2tT) {
    int bx = blockIdx.x;
    int t = threadIdx.x;
    if (bx < 4096) {
        // weight transpose+convert+tile: src [E][K][N] -> tiled [e][nt][kt][128][64]
        __shared__ float tile[64][65];
        bool isW1 = bx < 2048;
        int b = isW1 ? bx : bx - 2048;
        int e = b >> 8;
        int q = b & 255;
        int C = isW1 ? DH : DOUT;                 // N-dim
        int NTP = C >> 7;                         // n-tiles (16 / 4)
        int KTP = isW1 ? (DIN >> 6) : (DH >> 6);  // k-tiles (8 / 32)
        int rt = isW1 ? (q >> 5) : (q >> 3);      // k 64-tile idx
        int ct = isW1 ? (q & 31) : (q & 7);       // n 64-tile idx
        const float* s = (isW1 ? W1 : W2) + (size_t)e * (isW1 ? DIN * DH : DH * DOUT);
        u16* d = isW1 ? w1tT : w2tT;
        int r0 = rt * 64, c0 = ct * 64;
        for (int i = 0; i < 4; ++i) {
            int r = (t >> 4) + i * 16;
            int c = (t & 15) * 4;
            const float4 v = *(const float4*)&s[(size_t)(r0 + r) * C + c0 + c];
            tile[r][c] = v.x; tile[r][c + 1] = v.y; tile[r][c + 2] = v.z; tile[r][c + 3] = v.w;
        }
        __syncthreads();
        // 16B ushort8 stores: 8 consecutive k per lane (k 8-aligned -> one swizzle chunk)
        for (int i = 0; i < 2; ++i) {
            int c = (t >> 3) + i * 32;    // n-local 0..63
            int r = (t & 7) * 8;          // k-local, 8 consecutive
            int n = c0 + c, k = r0 + r;
            ushort8 o;
#pragma unroll
            for (int j = 0; j < 8; ++j) o[j] = f2bf(tile[r + j][c]);
            size_t off = ((size_t)(e * NTP + (n >> 7)) * KTP + (k >> 6)) * TILE
                         + slot_off(n & 127, k & 63);
            *(ushort8*)&d[off] = o;
        }
    } else {
        // gather-x: 4 rows per block, 64 lanes per row, 8 elems/lane
        int r = t >> 6, lane = t & 63;
        int i = (bx - 4096) * 4 + r;
        int pos = rpos[i];
        int k = lane * 8;
        const float4 a = *(const float4*)&x[(size_t)i * DIN + k];
        const float4 b = *(const float4*)&x[(size_t)i * DIN + k + 4];
        ushort8 o;
        o[0] = f2bf(a.x); o[1] = f2bf(a.y); o[2] = f2bf(a.z); o[3] = f2bf(a.w);
        o[4] = f2bf(b.x); o[5] = f2bf(b.y); o[6] = f2bf(b.z); o[7] = f2bf(b.w);
        int lp = pos & 127;
        size_t off = (size_t)(pos >> 7) * 8 * TILE + (size_t)(k >> 6) * TILE
                     + slot_off(lp, k & 63);
        *(ushort8*)&xsT[off] = o;
    }
}

// ---------------- 256x128-tile GEMM building blocks, 512-thread / 8-wave ----------------
// VGPR discipline (rounds 2-6): allocator budget defaults to 131072/(2*threads)
// = 128 for 512-thread blocks; acc[4][4] (64) + frags + addressing fits (r7
// measured 92-100). Per K-step LDS image: 3 slots {A0 rows 0-127, A1 rows
// 128-255, B n 0-127}, each a 128x64 pre-swizzled tile (16 KB).
// TRIPLE-buffered (3 x 48 KB = 144 KiB): counted-vmcnt pipeline (T4) -- at
// iter kt we issue stage(kt+2) then s_waitcnt vmcnt(12), which waits only for
// stage(kt)'s 6 loads, issued TWO compute phases earlier -> zero steady-state
// latency exposure (r6 drain-0 -> r7 counted: gemm_a 52 -> 40.5 us).
// Safety: stage(kt+2) overwrites the buffer consumed at iter kt-1 (all waves
// passed that iter's end barrier); each wave waits its OWN vmcnt then
// barriers (m201 pattern); sched_barrier(0) pins ds_reads below the wait.

#define LDF(base, row, c0) \
    (*(const bf16x8*)&(base)[(row) * 64 + ((((c0) ^ ((row) & 7))) << 3)])

// 512 threads x 16B = 8KB per gload round; 2 rounds per 16KB slot, 6 total
__device__ __forceinline__ void stage3(const u16* a0, const u16* a1, const u16* b,
                                       u16* buf, int soff, int doff) {
    __builtin_amdgcn_global_load_lds(GLOBAL_AS(a0 + soff), LDS_AS(buf + doff), 16, 0, 0);
    __builtin_amdgcn_global_load_lds(GLOBAL_AS(a0 + 4096 + soff), LDS_AS(buf + 4096 + doff), 16, 0, 0);
    __builtin_amdgcn_global_load_lds(GLOBAL_AS(a1 + soff), LDS_AS(buf + TILE + doff), 16, 0, 0);
    __builtin_amdgcn_global_load_lds(GLOBAL_AS(a1 + 4096 + soff), LDS_AS(buf + TILE + 4096 + doff), 16, 0, 0);
    __builtin_amdgcn_global_load_lds(GLOBAL_AS(b + soff), LDS_AS(buf + 2 * TILE + doff), 16, 0, 0);
    __builtin_amdgcn_global_load_lds(GLOBAL_AS(b + 4096 + soff), LDS_AS(buf + 2 * TILE + 4096 + doff), 16, 0, 0);
}

__device__ __forceinline__ void compute_step(const u16* At, const u16* Bt,
                                             int arow, int brow,
                                             floatx4 (&acc)[4][4], int q, int li) {
#pragma unroll
    for (int s = 0; s < 2; ++s) {
        int c0 = s * 4 + q;
        bf16x8 bfr[4];
#pragma unroll
        for (int fn = 0; fn < 4; ++fn) bfr[fn] = LDF(Bt, brow + fn * 16 + li, c0);
#pragma unroll
        for (int fm = 0; fm < 4; ++fm) {
            bf16x8 af = LDF(At, arow + fm * 16 + li, c0);
#pragma unroll
            for (int fn = 0; fn < 4; ++fn)
                acc[fm][fn] = __builtin_amdgcn_mfma_f32_16x16x32_bf16(
                    af, bfr[fn], acc[fm][fn], 0, 0, 0);
        }
    }
}

// counted-vmcnt triple-buffer K-loop (T4). sm = 9 slots (3 bufs x 3 slots).
template <int KT>
__device__ __forceinline__ void gemm_core3(const u16* a0, const u16* a1, const u16* b0,
                                           u16* sm, floatx4 (&acc)[4][4],
                                           int aslot, int arow, int brow,
                                           int q, int li, int soff, int doff) {
    stage3(a0, a1, b0, sm, soff, doff);                              // kt=0 -> buf0
    stage3(a0 + TILE, a1 + TILE, b0 + TILE, sm + 3 * TILE, soff, doff);  // kt=1 -> buf1
    int cur = 0;   // buffer index holding K-tile kt
#pragma unroll 1
    for (int kt = 0; kt < KT; ++kt) {
        if (kt + 2 < KT) {
            int nb = cur + 2; if (nb >= 3) nb -= 3;   // (kt+2)%3: held kt-1, dead since iter kt-1
            stage3(a0 + (size_t)(kt + 2) * TILE, a1 + (size_t)(kt + 2) * TILE,
                   b0 + (size_t)(kt + 2) * TILE, sm + (size_t)nb * 3 * TILE, soff, doff);
            asm volatile("s_waitcnt vmcnt(12)" ::: "memory");   // kt's 6 done; kt+1,kt+2 fly
        } else if (kt + 1 < KT) {
            asm volatile("s_waitcnt vmcnt(6)" ::: "memory");    // kt's done; kt+1 flies
        } else {
            asm volatile("s_waitcnt vmcnt(0)" ::: "memory");    // final drain
        }
        __builtin_amdgcn_s_barrier();
        __builtin_amdgcn_sched_barrier(0);   // pin ds_reads below the data-ready point
        const u16* At = sm + (size_t)(cur * 3 + aslot) * TILE;
        const u16* Bt = sm + (size_t)(cur * 3 + 2) * TILE;
        compute_step(At, Bt, arow, brow, acc, q, li);
        __builtin_amdgcn_s_barrier();        // WAR: all waves done reading before reuse
        cur = (cur == 2) ? 0 : cur + 1;
    }
}

// ---------------- pass A: h = relu(x @ W1 + b1), bf16 tiled out ----------------
// block tile 256m x 128n; grid = 8 experts x 16 n128-tiles x 5 m-slots = 640.
// 5 m-slots (not 4): expert counts are multinomial around 1024, so a count>1024
// needs a 5th m256-tile; with 4 slots that tile became a SECOND iteration on one
// block -> whole-kernel straggler tail (r7 Occupancy 13.9%). 5 slots = 1 tile/block.
__global__ __launch_bounds__(512) __attribute__((amdgpu_waves_per_eu(2)))
void gemm_a(const u16* __restrict__ At, const u16* __restrict__ Bt,
            const float* __restrict__ bias, u16* __restrict__ hsT,
            const int* __restrict__ cnt, const int* __restrict__ offs) {
    __shared__ u16 sm[3 * 3 * TILE];   // 144 KiB
    int bx = blockIdx.x;
    int e = bx & 7;
    int r = bx >> 3;
    int nt = r & 15;
    int mt0 = r >> 4;
    int count = cnt[e];
    int base128 = offs[e] >> 7;
    int tid = threadIdx.x;
    int w = tid >> 6, l = tid & 63, q = l >> 4, li = l & 15;
    int wm = w >> 1, wn = w & 1;
    int aslot = wm >> 1, arow = (wm & 1) * 64, brow = wn * 64;
    int soff = tid * 8, doff = w * 512;
#pragma unroll 1
    for (int mt = mt0; mt * 256 < count; mt += 5) {
        const u16* a0 = At + (size_t)((base128 + mt * 2 + 0) * 8) * TILE;
        const u16* a1 = At + (size_t)((base128 + mt * 2 + 1) * 8) * TILE;
        const u16* b0 = Bt + (size_t)((e * 16 + nt) * 8) * TILE;
        floatx4 acc[4][4];
#pragma unroll
        for (int a = 0; a < 4; ++a)
#pragma unroll
            for (int b = 0; b < 4; ++b) acc[a][b] = (floatx4)0.0f;

        gemm_core3<8>(a0, a1, b0, sm, acc, aslot, arow, brow, q, li, soff, doff);

        // epilogue: wave owns 64x64; swizzled image in private 8 KB LDS region,
        // then fully-contiguous dump (lane-16B reads, conflict-free)
        float bv[4];
#pragma unroll
        for (int fn = 0; fn < 4; ++fn)
            bv[fn] = bias[(size_t)e * DH + nt * 128 + wn * 64 + fn * 16 + li];
        u16* img = sm + (size_t)w * 4096;
#pragma unroll
        for (int fm = 0; fm < 4; ++fm)
#pragma unroll
            for (int fn = 0; fn < 4; ++fn)
#pragma unroll
                for (int rr = 0; rr < 4; ++rr) {
                    float v = acc[fm][fn][rr] + bv[fn];
                    v = v > 0.0f ? v : 0.0f;
                    int row = fm * 16 + q * 4 + rr;   // 0..63 (wave-local m)
                    int col = fn * 16 + li;           // 0..63 (k-local in hsT tile)
                    img[row * 64 + ((((col >> 3) ^ (row & 7)) << 3) | (col & 7))] = f2bf(v);
                }
        // own-region write->read within one wave: in-order DS + compiler lgkmcnt
        if ((mt * 2 + aslot) * 128 < count) {   // guard vs expert segment end
            u16* dst = hsT + ((size_t)(base128 + mt * 2 + aslot) * 32 + nt * 2 + wn) * TILE
                       + (wm & 1) * 4096;
#pragma unroll
            for (int j = 0; j < 8; ++j)
                *(ushort8*)&dst[j * 512 + l * 8] = *(const ushort8*)&img[j * 512 + l * 8];
        }
        __syncthreads();   // img regions reused as staging buffers next m-iter
    }
}

// ---------------- pass B: partial[ks] = h @ W2 over K-half, fp32 sorted layout ----------
// block tile 256m x 128n; grid = 8 experts x 4 n128 x 2 ks x 5 m-slots = 320
__global__ __launch_bounds__(512) __attribute__((amdgpu_waves_per_eu(2)))
void gemm_b(const u16* __restrict__ At, const u16* __restrict__ Bt,
            float* __restrict__ ps, const int* __restrict__ cnt,
            const int* __restrict__ offs) {
    __shared__ u16 sm[3 * 3 * TILE];   // 144 KiB
    int bx = blockIdx.x;
    int e = bx & 7;
    int r = bx >> 3;
    int nt = r & 3;
    int ks = (r >> 2) & 1;
    int mt0 = r >> 3;
    int count = cnt[e];
    int seg = offs[e];
    int base128 = seg >> 7;
    int tid = threadIdx.x;
    int w = tid >> 6, l = tid & 63, q = l >> 4, li = l & 15;
    int wm = w >> 1, wn = w & 1;
    int aslot = wm >> 1, arow = (wm & 1) * 64, brow = wn * 64;
    int soff = tid * 8, doff = w * 512;
#pragma unroll 1
    for (int mt = mt0; mt * 256 < count; mt += 5) {
        const u16* a0 = At + (size_t)((base128 + mt * 2 + 0) * 32 + ks * 16) * TILE;
        const u16* a1 = At + (size_t)((base128 + mt * 2 + 1) * 32 + ks * 16) * TILE;
        const u16* b0 = Bt + (size_t)((e * 4 + nt) * 32 + ks * 16) * TILE;
        floatx4 acc[4][4];
#pragma unroll
        for (int a = 0; a < 4; ++a)
#pragma unroll
            for (int b = 0; b < 4; ++b) acc[a][b] = (floatx4)0.0f;

        gemm_core3<16>(a0, a1, b0, sm, acc, aslot, arow, brow, q, li, soff, doff);

        // direct fp32 stores; guard per 128-row half against segment overflow
        if ((mt * 2 + aslot) * 128 < count) {
            float* pbase = ps + ((size_t)ks * ROWCAP + seg + (size_t)mt * 256) * DOUT;
#pragma unroll
            for (int fn = 0; fn < 4; ++fn) {
                int col = nt * 128 + wn * 64 + fn * 16 + li;
#pragma unroll
                for (int fm = 0; fm < 4; ++fm) {
                    int row0 = wm * 64 + fm * 16 + q * 4;
#pragma unroll
                    for (int rr = 0; rr < 4; ++rr)
                        pbase[(size_t)(row0 + rr) * DOUT + col] = acc[fm][fn][rr];
                }
            }
        }
        __syncthreads();   // LDS reuse across m-iterations
    }
}

// ---------------- reduce: out[i] = ps[0][rpos[i]] + ps[1][rpos[i]] + b2[groups[i]] ------
__global__ __launch_bounds__(256) void reduce_b(
        const float* __restrict__ ps, const int* __restrict__ rpos,
        const int* __restrict__ groups, const float* __restrict__ b2,
        float* __restrict__ out) {
    int idx = blockIdx.x * 256 + threadIdx.x;
    int i = idx >> 7;
    int c = (idx & 127) * 4;
    int pos = rpos[i];
    int g = groups[i];
    const float4 v0 = *(const float4*)&ps[(size_t)pos * DOUT + c];
    const float4 v1 = *(const float4*)&ps[((size_t)ROWCAP + pos) * DOUT + c];
    const float4 bb = *(const float4*)&b2[(size_t)g * DOUT + c];
    float4 o;
    o.x = v0.x + v1.x + bb.x; o.y = v0.y + v1.y + bb.y;
    o.z = v0.z + v1.z + bb.z; o.w = v0.w + v1.w + bb.w;
    *(float4*)&out[(size_t)i * DOUT + c] = o;
}

// ---------------- launch ----------------
extern "C" void kernel_launch(void* const* d_in, const int* in_sizes, int n_in,
                              void* d_out, int out_size, void* d_ws, size_t ws_size,
                              hipStream_t stream) {
    const float* x = (const float*)d_in[0];
    const int* groups = (const int*)d_in[1];
    const float* W1 = (const float*)d_in[2];
    const float* b1 = (const float*)d_in[3];
    const float* W2 = (const float*)d_in[4];
    const float* b2 = (const float*)d_in[5];
    float* out = (float*)d_out;

    char* ws = (char*)d_ws;
    size_t o = 0;
    auto alloc = [&](size_t bytes) {
        void* p = ws + o;
        o = (o + bytes + 255) & ~(size_t)255;
        return p;
    };
    int* cnt = (int*)alloc(NEXP * 4);
    int* offs = (int*)alloc(NEXP * 4);
    int* perm = (int*)alloc((size_t)ROWCAP * 4);
    int* rpos = (int*)alloc((size_t)NB * 4);
    u16* xsT = (u16*)alloc((size_t)(RCAPRD / 128) * 8 * TILE * 2);    // ~10.5 MB (read-pad)
    u16* w1tT = (u16*)alloc((size_t)NEXP * DIN * DH * 2);             // 16.8 MB
    u16* w2tT = (u16*)alloc((size_t)NEXP * DH * DOUT * 2);            // 16.8 MB
    u16* hsT = (u16*)alloc((size_t)(RCAPRD / 128) * 32 * TILE * 2);   // ~41.9 MB (read-pad)
    float* ps = (float*)alloc((size_t)2 * ROWCAP * DOUT * 4);         // ~37.7 MB

    route_kernel<<<1, 1024, 0, stream>>>(groups, cnt, offs, perm, rpos);
    prep_kernel<<<6144, 256, 0, stream>>>(x, W1, W2, rpos, xsT, w1tT, w2tT);
    gemm_a<<<NEXP * 16 * 5, 512, 0, stream>>>(xsT, w1tT, b1, hsT, cnt, offs);
    gemm_b<<<NEXP * 4 * 2 * 5, 512, 0, stream>>>(hsT, w2tT, ps, cnt, offs);
    reduce_b<<<(NB * (DOUT / 4)) / 256, 256, 0, stream>>>(ps, rpos, groups, b2, out);
}

// Round 10
// 205.954 us; speedup vs baseline: 1.1153x; 1.0687x over previous
//
#include <hip/hip_runtime.h>
#include <hip/hip_bf16.h>

typedef unsigned short u16;
typedef __bf16 bf16x8 __attribute__((ext_vector_type(8)));
typedef float floatx4 __attribute__((ext_vector_type(4)));
typedef unsigned short ushort8 __attribute__((ext_vector_type(8)));

#define GLOBAL_AS(p) ((const __attribute__((address_space(1))) void*)(p))
#define LDS_AS(p) ((__attribute__((address_space(3))) void*)(p))

constexpr int NB = 8192;
constexpr int DIN = 512;
constexpr int DH = 2048;
constexpr int DOUT = 512;
constexpr int NEXP = 8;
constexpr int ROWCAP = NB + NEXP * 128;    // 128-padded segments (write-side bound)
constexpr int RCAPRD = NB + NEXP * 256;    // read-side row capacity (kept from r5-r8 layout)
constexpr int TILE = 8192;                 // elements in a 128x64 bf16 tile

__device__ __forceinline__ u16 f2bf(float f) {
    unsigned u = __builtin_bit_cast(unsigned, f);
    unsigned r = u + 0x7FFFu + ((u >> 16) & 1u);
    return (u16)(r >> 16);
}

// element offset within a 128x64 tile for (row, klocal), xor-swizzled 16B chunks
__device__ __forceinline__ int slot_off(int row, int kl) {
    return row * 64 + ((((kl >> 3) ^ (row & 7)) << 3) | (kl & 7));
}

// ---------------- routing: one single-block kernel, 1024 threads / 16 waves ----------------
__global__ __launch_bounds__(1024) void route_kernel(
        const int* __restrict__ groups, int* __restrict__ cnt,
        int* __restrict__ offs, int* __restrict__ perm, int* __restrict__ rpos) {
    __shared__ int wc[NEXP * 16];    // [e][wave] counts
    __shared__ int lcur[NEXP * 16];  // running positions
    int t = threadIdx.x;
    int w = t >> 6;
    if (t < NEXP * 16) wc[t] = 0;
    __syncthreads();
    for (int i = t; i < NB; i += 1024) atomicAdd(&wc[groups[i] * 16 + w], 1);
    __syncthreads();
    if (t == 0) {
        int run = 0;
        for (int e = 0; e < NEXP; ++e) {
            offs[e] = run;
            int s = run;
            for (int j = 0; j < 16; ++j) { lcur[e * 16 + j] = s; s += wc[e * 16 + j]; }
            cnt[e] = s - run;
            run += (((s - run) + 127) >> 7) << 7;   // 128-aligned segments
        }
    }
    __syncthreads();
    for (int i = t; i < NB; i += 1024) {
        int e = groups[i];
        int pos = atomicAdd(&lcur[e * 16 + w], 1);
        perm[pos] = i;
        rpos[i] = pos;
    }
}

// ---------------- fused wide prep: W1/W2 transpose+tile | gather-x ----------------
// grid.x = 4096 (weights) + 2048 (gather) = 6144
__global__ __launch_bounds__(256) void prep_kernel(
        const float* __restrict__ x, const float* __restrict__ W1,
        const float* __restrict__ W2, const int* __restrict__ rpos,
        u16* __restrict__ xsT, u16* __restrict__ w1tT, u16* __restrict__ w2tT) {
    int bx = blockIdx.x;
    int t = threadIdx.x;
    if (bx < 4096) {
        // weight transpose+convert+tile: src [E][K][N] -> tiled [e][nt][kt][128][64]
        __shared__ float tile[64][65];
        bool isW1 = bx < 2048;
        int b = isW1 ? bx : bx - 2048;
        int e = b >> 8;
        int q = b & 255;
        int C = isW1 ? DH : DOUT;                 // N-dim
        int NTP = C >> 7;                         // n-tiles (16 / 4)
        int KTP = isW1 ? (DIN >> 6) : (DH >> 6);  // k-tiles (8 / 32)
        int rt = isW1 ? (q >> 5) : (q >> 3);      // k 64-tile idx
        int ct = isW1 ? (q & 31) : (q & 7);       // n 64-tile idx
        const float* s = (isW1 ? W1 : W2) + (size_t)e * (isW1 ? DIN * DH : DH * DOUT);
        u16* d = isW1 ? w1tT : w2tT;
        int r0 = rt * 64, c0 = ct * 64;
        for (int i = 0; i < 4; ++i) {
            int r = (t >> 4) + i * 16;
            int c = (t & 15) * 4;
            const float4 v = *(const float4*)&s[(size_t)(r0 + r) * C + c0 + c];
            tile[r][c] = v.x; tile[r][c + 1] = v.y; tile[r][c + 2] = v.z; tile[r][c + 3] = v.w;
        }
        __syncthreads();
        // 16B ushort8 stores: 8 consecutive k per lane (k 8-aligned -> one swizzle chunk)
        for (int i = 0; i < 2; ++i) {
            int c = (t >> 3) + i * 32;    // n-local 0..63
            int r = (t & 7) * 8;          // k-local, 8 consecutive
            int n = c0 + c, k = r0 + r;
            ushort8 o;
#pragma unroll
            for (int j = 0; j < 8; ++j) o[j] = f2bf(tile[r + j][c]);
            size_t off = ((size_t)(e * NTP + (n >> 7)) * KTP + (k >> 6)) * TILE
                         + slot_off(n & 127, k & 63);
            *(ushort8*)&d[off] = o;
        }
    } else {
        // gather-x: 4 rows per block, 64 lanes per row, 8 elems/lane
        int r = t >> 6, lane = t & 63;
        int i = (bx - 4096) * 4 + r;
        int pos = rpos[i];
        int k = lane * 8;
        const float4 a = *(const float4*)&x[(size_t)i * DIN + k];
        const float4 b = *(const float4*)&x[(size_t)i * DIN + k + 4];
        ushort8 o;
        o[0] = f2bf(a.x); o[1] = f2bf(a.y); o[2] = f2bf(a.z); o[3] = f2bf(a.w);
        o[4] = f2bf(b.x); o[5] = f2bf(b.y); o[6] = f2bf(b.z); o[7] = f2bf(b.w);
        int lp = pos & 127;
        size_t off = (size_t)(pos >> 7) * 8 * TILE + (size_t)(k >> 6) * TILE
                     + slot_off(lp, k & 63);
        *(ushort8*)&xsT[off] = o;
    }
}

// ---------------- 128x128-tile GEMM core, 256-thread / 4-wave, 2 blocks/CU ------------
// Co-residency design (m97/m114: sibling block's waves issue while this block
// waits): LDS = 2 bufs x {A,B} x 16KB = 64KB -> 2 blocks/CU. VGPR budget for
// 256-thr blocks = 256; acc[4][4]=64 + frags ~130 fits.
// RACE-SAFE schedule (r9 post-mortem: issuing stage BEFORE the barriers left
// the WAR target only one raw s_barrier away with no compile-time fence ->
// scheduler could hoist gload_lds writes into sibling waves' read window ->
// intermittent corruption, tripwire). Here stage(kt+1) is issued AFTER the
// top barrier, inside the compute region:
//   WAR: buf[cur^1] last read at compute(kt-1), separated by end-barrier(kt-1)
//        + top-barrier(kt) + sched_barrier(0) fences = 2 barriers, hoist-proof.
//   RAW: each wave drains its OWN stage(kt) loads (vmcnt(0)) then barriers
//        (m201 pattern); loads had all of compute(kt-1) to fly, and the
//        co-resident sibling block hides the residual drain (m114 overlap).

#define LDF(base, row, c0) \
    (*(const bf16x8*)&(base)[(row) * 64 + ((((c0) ^ ((row) & 7))) << 3)])

// stage one K-step: A tile + B tile (16KB each). 256 thr x 16B = 4KB per gload,
// 4 gloads per slot, 8 per step.
__device__ __forceinline__ void stage2(const u16* a, const u16* b,
                                       u16* buf, int soff, int doff) {
#pragma unroll
    for (int ch = 0; ch < 4; ++ch) {
        __builtin_amdgcn_global_load_lds(GLOBAL_AS(a + ch * 2048 + soff),
                                         LDS_AS(buf + ch * 2048 + doff), 16, 0, 0);
        __builtin_amdgcn_global_load_lds(GLOBAL_AS(b + ch * 2048 + soff),
                                         LDS_AS(buf + TILE + ch * 2048 + doff), 16, 0, 0);
    }
}

__device__ __forceinline__ void compute_step(const u16* At, const u16* Bt,
                                             int arow, int brow,
                                             floatx4 (&acc)[4][4], int q, int li) {
#pragma unroll
    for (int s = 0; s < 2; ++s) {
        int c0 = s * 4 + q;
        bf16x8 bfr[4];
#pragma unroll
        for (int fn = 0; fn < 4; ++fn) bfr[fn] = LDF(Bt, brow + fn * 16 + li, c0);
#pragma unroll
        for (int fm = 0; fm < 4; ++fm) {
            bf16x8 af = LDF(At, arow + fm * 16 + li, c0);
#pragma unroll
            for (int fn = 0; fn < 4; ++fn)
                acc[fm][fn] = __builtin_amdgcn_mfma_f32_16x16x32_bf16(
                    af, bfr[fn], acc[fm][fn], 0, 0, 0);
        }
    }
}

// double-buffer K-loop, stage-after-barrier (race-safe), per-wave vmcnt drain.
template <int KT>
__device__ __forceinline__ void gemm_core2(const u16* a0, const u16* b0,
                                           u16* sm, floatx4 (&acc)[4][4],
                                           int arow, int brow,
                                           int q, int li, int soff, int doff) {
    stage2(a0, b0, sm, soff, doff);   // kt=0 -> buf0
    int cur = 0;
#pragma unroll 1
    for (int kt = 0; kt < KT; ++kt) {
        asm volatile("s_waitcnt vmcnt(0)" ::: "memory");  // own stage(kt) loads landed
        __builtin_amdgcn_s_barrier();                     // all waves' stage(kt) visible
        __builtin_amdgcn_sched_barrier(0);                // nothing crosses above (rule 18)
        if (kt + 1 < KT)
            stage2(a0 + (size_t)(kt + 1) * TILE, b0 + (size_t)(kt + 1) * TILE,
                   sm + (size_t)(cur ^ 1) * 2 * TILE, soff, doff);
        const u16* At = sm + (size_t)(cur * 2 + 0) * TILE;
        const u16* Bt = sm + (size_t)(cur * 2 + 1) * TILE;
        compute_step(At, Bt, arow, brow, acc, q, li);
        __builtin_amdgcn_sched_barrier(0);                // reads can't sink past end barrier
        __builtin_amdgcn_s_barrier();                     // end: all reads of buf[cur] done
        cur ^= 1;
    }
}

// ---------------- pass A: h = relu(x @ W1 + b1), bf16 tiled out ----------------
// block tile 128m x 128n; grid = 8 experts x 16 n128-tiles x 9 m-slots = 1152.
// Waves 2x2: wm=w>>1 (m64 half), wn=w&1 (n64 half); per-wave 64x64, acc[4][4].
__global__ __launch_bounds__(256) __attribute__((amdgpu_waves_per_eu(2)))
void gemm_a(const u16* __restrict__ At, const u16* __restrict__ Bt,
            const float* __restrict__ bias, u16* __restrict__ hsT,
            const int* __restrict__ cnt, const int* __restrict__ offs) {
    __shared__ u16 sm[2 * 2 * TILE];   // 64 KiB
    int bx = blockIdx.x;
    int e = bx & 7;
    int r = bx >> 3;
    int nt = r & 15;
    int mt0 = r >> 4;
    int count = cnt[e];
    int base128 = offs[e] >> 7;
    int tid = threadIdx.x;
    int w = tid >> 6, l = tid & 63, q = l >> 4, li = l & 15;
    int wm = w >> 1, wn = w & 1;
    int arow = wm * 64, brow = wn * 64;
    int soff = tid * 8, doff = w * 512;
#pragma unroll 1
    for (int mt = mt0; mt * 128 < count; mt += 9) {
        const u16* a0 = At + (size_t)((base128 + mt) * 8) * TILE;
        const u16* b0 = Bt + (size_t)((e * 16 + nt) * 8) * TILE;
        floatx4 acc[4][4];
#pragma unroll
        for (int a = 0; a < 4; ++a)
#pragma unroll
            for (int b = 0; b < 4; ++b) acc[a][b] = (floatx4)0.0f;

        gemm_core2<8>(a0, b0, sm, acc, arow, brow, q, li, soff, doff);

        // epilogue: wave owns 64x64; swizzled image in private 8 KB LDS region
        // (= buf0 slots, last read 2+ barriers ago; all gloads drained), dump
        // contiguous. Own-region write->read within one wave: in-order DS ops.
        float bv[4];
#pragma unroll
        for (int fn = 0; fn < 4; ++fn)
            bv[fn] = bias[(size_t)e * DH + nt * 128 + wn * 64 + fn * 16 + li];
        u16* img = sm + (size_t)w * 4096;
#pragma unroll
        for (int fm = 0; fm < 4; ++fm)
#pragma unroll
            for (int fn = 0; fn < 4; ++fn)
#pragma unroll
                for (int rr = 0; rr < 4; ++rr) {
                    float v = acc[fm][fn][rr] + bv[fn];
                    v = v > 0.0f ? v : 0.0f;
                    int row = fm * 16 + q * 4 + rr;   // 0..63 (wave-local m)
                    int col = fn * 16 + li;           // 0..63 (k-local in hsT tile)
                    img[row * 64 + ((((col >> 3) ^ (row & 7)) << 3) | (col & 7))] = f2bf(v);
                }
        u16* dst = hsT + ((size_t)(base128 + mt) * 32 + nt * 2 + wn) * TILE + wm * 4096;
#pragma unroll
        for (int j = 0; j < 8; ++j)
            *(ushort8*)&dst[j * 512 + l * 8] = *(const ushort8*)&img[j * 512 + l * 8];
        __syncthreads();   // img regions reused as staging buffers next m-iter
    }
}

// ---------------- pass B: partial[ks] = h @ W2 over K-half, fp32 sorted layout ----------
// block tile 128m x 128n; grid = 8 experts x 4 n128 x 2 ks x 9 m-slots = 576
__global__ __launch_bounds__(256) __attribute__((amdgpu_waves_per_eu(2)))
void gemm_b(const u16* __restrict__ At, const u16* __restrict__ Bt,
            float* __restrict__ ps, const int* __restrict__ cnt,
            const int* __restrict__ offs) {
    __shared__ u16 sm[2 * 2 * TILE];   // 64 KiB
    int bx = blockIdx.x;
    int e = bx & 7;
    int r = bx >> 3;
    int nt = r & 3;
    int ks = (r >> 2) & 1;
    int mt0 = r >> 3;
    int count = cnt[e];
    int seg = offs[e];
    int base128 = seg >> 7;
    int tid = threadIdx.x;
    int w = tid >> 6, l = tid & 63, q = l >> 4, li = l & 15;
    int wm = w >> 1, wn = w & 1;
    int arow = wm * 64, brow = wn * 64;
    int soff = tid * 8, doff = w * 512;
#pragma unroll 1
    for (int mt = mt0; mt * 128 < count; mt += 9) {
        const u16* a0 = At + (size_t)((base128 + mt) * 32 + ks * 16) * TILE;
        const u16* b0 = Bt + (size_t)((e * 4 + nt) * 32 + ks * 16) * TILE;
        floatx4 acc[4][4];
#pragma unroll
        for (int a = 0; a < 4; ++a)
#pragma unroll
            for (int b = 0; b < 4; ++b) acc[a][b] = (floatx4)0.0f;

        gemm_core2<16>(a0, b0, sm, acc, arow, brow, q, li, soff, doff);

        // direct fp32 stores (padding rows land in this expert's ps segment padding:
        // tile mt with mt*128<count is fully inside the ceil(count/128)*128 segment)
        float* pbase = ps + ((size_t)ks * ROWCAP + seg + (size_t)mt * 128) * DOUT;
#pragma unroll
        for (int fn = 0; fn < 4; ++fn) {
            int col = nt * 128 + wn * 64 + fn * 16 + li;
#pragma unroll
            for (int fm = 0; fm < 4; ++fm) {
                int row0 = wm * 64 + fm * 16 + q * 4;
#pragma unroll
                for (int rr = 0; rr < 4; ++rr)
                    pbase[(size_t)(row0 + rr) * DOUT + col] = acc[fm][fn][rr];
            }
        }
        __syncthreads();   // LDS reuse across m-iterations
    }
}

// ---------------- reduce: out[i] = ps[0][rpos[i]] + ps[1][rpos[i]] + b2[groups[i]] ------
__global__ __launch_bounds__(256) void reduce_b(
        const float* __restrict__ ps, const int* __restrict__ rpos,
        const int* __restrict__ groups, const float* __restrict__ b2,
        float* __restrict__ out) {
    int idx = blockIdx.x * 256 + threadIdx.x;
    int i = idx >> 7;
    int c = (idx & 127) * 4;
    int pos = rpos[i];
    int g = groups[i];
    const float4 v0 = *(const float4*)&ps[(size_t)pos * DOUT + c];
    const float4 v1 = *(const float4*)&ps[((size_t)ROWCAP + pos) * DOUT + c];
    const float4 bb = *(const float4*)&b2[(size_t)g * DOUT + c];
    float4 o;
    o.x = v0.x + v1.x + bb.x; o.y = v0.y + v1.y + bb.y;
    o.z = v0.z + v1.z + bb.z; o.w = v0.w + v1.w + bb.w;
    *(float4*)&out[(size_t)i * DOUT + c] = o;
}

// ---------------- launch ----------------
extern "C" void kernel_launch(void* const* d_in, const int* in_sizes, int n_in,
                              void* d_out, int out_size, void* d_ws, size_t ws_size,
                              hipStream_t stream) {
    const float* x = (const float*)d_in[0];
    const int* groups = (const int*)d_in[1];
    const float* W1 = (const float*)d_in[2];
    const float* b1 = (const float*)d_in[3];
    const float* W2 = (const float*)d_in[4];
    const float* b2 = (const float*)d_in[5];
    float* out = (float*)d_out;

    char* ws = (char*)d_ws;
    size_t o = 0;
    auto alloc = [&](size_t bytes) {
        void* p = ws + o;
        o = (o + bytes + 255) & ~(size_t)255;
        return p;
    };
    int* cnt = (int*)alloc(NEXP * 4);
    int* offs = (int*)alloc(NEXP * 4);
    int* perm = (int*)alloc((size_t)ROWCAP * 4);
    int* rpos = (int*)alloc((size_t)NB * 4);
    u16* xsT = (u16*)alloc((size_t)(RCAPRD / 128) * 8 * TILE * 2);    // ~10.5 MB
    u16* w1tT = (u16*)alloc((size_t)NEXP * DIN * DH * 2);             // 16.8 MB
    u16* w2tT = (u16*)alloc((size_t)NEXP * DH * DOUT * 2);            // 16.8 MB
    u16* hsT = (u16*)alloc((size_t)(RCAPRD / 128) * 32 * TILE * 2);   // ~41.9 MB
    float* ps = (float*)alloc((size_t)2 * ROWCAP * DOUT * 4);         // ~37.7 MB

    route_kernel<<<1, 1024, 0, stream>>>(groups, cnt, offs, perm, rpos);
    prep_kernel<<<6144, 256, 0, stream>>>(x, W1, W2, rpos, xsT, w1tT, w2tT);
    gemm_a<<<NEXP * 16 * 9, 256, 0, stream>>>(xsT, w1tT, b1, hsT, cnt, offs);
    gemm_b<<<NEXP * 4 * 2 * 9, 256, 0, stream>>>(hsT, w2tT, ps, cnt, offs);
    reduce_b<<<(NB * (DOUT / 4)) / 256, 256, 0, stream>>>(ps, rpos, groups, b2, out);
}

// Round 11
// 197.512 us; speedup vs baseline: 1.1629x; 1.0427x over previous
//
#include <hip/hip_runtime.h>
#include <hip/hip_bf16.h>

typedef unsigned short u16;
typedef __bf16 bf16x8 __attribute__((ext_vector_type(8)));
typedef float floatx4 __attribute__((ext_vector_type(4)));
typedef unsigned short ushort8 __attribute__((ext_vector_type(8)));

#define GLOBAL_AS(p) ((const __attribute__((address_space(1))) void*)(p))
#define LDS_AS(p) ((__attribute__((address_space(3))) void*)(p))

constexpr int NB = 8192;
constexpr int DIN = 512;
constexpr int DH = 2048;
constexpr int DOUT = 512;
constexpr int NEXP = 8;
constexpr int ROWCAP = NB + NEXP * 128;    // 128-padded segments
constexpr int RCAPRD = NB + NEXP * 256;    // read-side row capacity (layout kept from r5+)
constexpr int TILE = 8192;                 // elements in a 128x64 bf16 tile

__device__ __forceinline__ u16 f2bf(float f) {
    unsigned u = __builtin_bit_cast(unsigned, f);
    unsigned r = u + 0x7FFFu + ((u >> 16) & 1u);
    return (u16)(r >> 16);
}

// element offset within a 128x64 tile for (row, klocal), xor-swizzled 16B chunks
__device__ __forceinline__ int slot_off(int row, int kl) {
    return row * 64 + ((((kl >> 3) ^ (row & 7)) << 3) | (kl & 7));
}

// ---------------- routing: one single-block kernel, 1024 threads / 16 waves ----------------
__global__ __launch_bounds__(1024) void route_kernel(
        const int* __restrict__ groups, int* __restrict__ cnt,
        int* __restrict__ offs, int* __restrict__ perm, int* __restrict__ rpos) {
    __shared__ int wc[NEXP * 16];    // [e][wave] counts
    __shared__ int lcur[NEXP * 16];  // running positions
    int t = threadIdx.x;
    int w = t >> 6;
    if (t < NEXP * 16) wc[t] = 0;
    __syncthreads();
    for (int i = t; i < NB; i += 1024) atomicAdd(&wc[groups[i] * 16 + w], 1);
    __syncthreads();
    if (t == 0) {
        int run = 0;
        for (int e = 0; e < NEXP; ++e) {
            offs[e] = run;
            int s = run;
            for (int j = 0; j < 16; ++j) { lcur[e * 16 + j] = s; s += wc[e * 16 + j]; }
            cnt[e] = s - run;
            run += (((s - run) + 127) >> 7) << 7;   // 128-aligned segments
        }
    }
    __syncthreads();
    for (int i = t; i < NB; i += 1024) {
        int e = groups[i];
        int pos = atomicAdd(&lcur[e * 16 + w], 1);
        perm[pos] = i;
        rpos[i] = pos;
    }
}

// ---------------- fused wide prep: W1/W2 transpose+tile | gather-x ----------------
// grid.x = 4096 (weights) + 2048 (gather) = 6144
__global__ __launch_bounds__(256) void prep_kernel(
        const float* __restrict__ x, const float* __restrict__ W1,
        const float* __restrict__ W2, const int* __restrict__ rpos,
        u16* __restrict__ xsT, u16* __restrict__ w1tT, u16* __restrict__ w2tT) {
    int bx = blockIdx.x;
    int t = threadIdx.x;
    if (bx < 4096) {
        // weight transpose+convert+tile: src [E][K][N] -> tiled [e][nt][kt][128][64]
        __shared__ float tile[64][65];
        bool isW1 = bx < 2048;
        int b = isW1 ? bx : bx - 2048;
        int e = b >> 8;
        int q = b & 255;
        int C = isW1 ? DH : DOUT;                 // N-dim
        int NTP = C >> 7;                         // n-tiles (16 / 4)
        int KTP = isW1 ? (DIN >> 6) : (DH >> 6);  // k-tiles (8 / 32)
        int rt = isW1 ? (q >> 5) : (q >> 3);      // k 64-tile idx
        int ct = isW1 ? (q & 31) : (q & 7);       // n 64-tile idx
        const float* s = (isW1 ? W1 : W2) + (size_t)e * (isW1 ? DIN * DH : DH * DOUT);
        u16* d = isW1 ? w1tT : w2tT;
        int r0 = rt * 64, c0 = ct * 64;
        for (int i = 0; i < 4; ++i) {
            int r = (t >> 4) + i * 16;
            int c = (t & 15) * 4;
            const float4 v = *(const float4*)&s[(size_t)(r0 + r) * C + c0 + c];
            tile[r][c] = v.x; tile[r][c + 1] = v.y; tile[r][c + 2] = v.z; tile[r][c + 3] = v.w;
        }
        __syncthreads();
        // 16B ushort8 stores: 8 consecutive k per lane (k 8-aligned -> one swizzle chunk)
        for (int i = 0; i < 2; ++i) {
            int c = (t >> 3) + i * 32;    // n-local 0..63
            int r = (t & 7) * 8;          // k-local, 8 consecutive
            int n = c0 + c, k = r0 + r;
            ushort8 o;
#pragma unroll
            for (int j = 0; j < 8; ++j) o[j] = f2bf(tile[r + j][c]);
            size_t off = ((size_t)(e * NTP + (n >> 7)) * KTP + (k >> 6)) * TILE
                         + slot_off(n & 127, k & 63);
            *(ushort8*)&d[off] = o;
        }
    } else {
        // gather-x: 4 rows per block, 64 lanes per row, 8 elems/lane
        int r = t >> 6, lane = t & 63;
        int i = (bx - 4096) * 4 + r;
        int pos = rpos[i];
        int k = lane * 8;
        const float4 a = *(const float4*)&x[(size_t)i * DIN + k];
        const float4 b = *(const float4*)&x[(size_t)i * DIN + k + 4];
        ushort8 o;
        o[0] = f2bf(a.x); o[1] = f2bf(a.y); o[2] = f2bf(a.z); o[3] = f2bf(a.w);
        o[4] = f2bf(b.x); o[5] = f2bf(b.y); o[6] = f2bf(b.z); o[7] = f2bf(b.w);
        int lp = pos & 127;
        size_t off = (size_t)(pos >> 7) * 8 * TILE + (size_t)(k >> 6) * TILE
                     + slot_off(lp, k & 63);
        *(ushort8*)&xsT[off] = o;
    }
}

// ---------------- GEMM fragment compute (shared by both passes) ----------------
#define LDF(base, row, c0) \
    (*(const bf16x8*)&(base)[(row) * 64 + ((((c0) ^ ((row) & 7))) << 3)])

__device__ __forceinline__ void compute_step(const u16* At, const u16* Bt,
                                             int arow, int brow,
                                             floatx4 (&acc)[4][4], int q, int li) {
#pragma unroll
    for (int s = 0; s < 2; ++s) {
        int c0 = s * 4 + q;
        bf16x8 bfr[4];
#pragma unroll
        for (int fn = 0; fn < 4; ++fn) bfr[fn] = LDF(Bt, brow + fn * 16 + li, c0);
#pragma unroll
        for (int fm = 0; fm < 4; ++fm) {
            bf16x8 af = LDF(At, arow + fm * 16 + li, c0);
#pragma unroll
            for (int fn = 0; fn < 4; ++fn)
                acc[fm][fn] = __builtin_amdgcn_mfma_f32_16x16x32_bf16(
                    af, bfr[fn], acc[fm][fn], 0, 0, 0);
        }
    }
}

// ---------------- pass A: 128x128-tile, 256-thr / 4-wave, 2 blocks/CU (r10-proven) -----
// stage one K-step: A tile + B tile (16KB each). 256 thr x 16B = 4KB per gload.
__device__ __forceinline__ void stage2(const u16* a, const u16* b,
                                       u16* buf, int soff, int doff) {
#pragma unroll
    for (int ch = 0; ch < 4; ++ch) {
        __builtin_amdgcn_global_load_lds(GLOBAL_AS(a + ch * 2048 + soff),
                                         LDS_AS(buf + ch * 2048 + doff), 16, 0, 0);
        __builtin_amdgcn_global_load_lds(GLOBAL_AS(b + ch * 2048 + soff),
                                         LDS_AS(buf + TILE + ch * 2048 + doff), 16, 0, 0);
    }
}

// race-safe double-buffer K-loop (r10): stage AFTER top barrier, own-vmcnt drain.
//   WAR: buf[cur^1] last read at compute(kt-1), 2 barriers + sched fences away.
//   RAW: own stage(kt) drained via vmcnt(0); sibling block hides drain (m114).
template <int KT>
__device__ __forceinline__ void gemm_core2(const u16* a0, const u16* b0,
                                           u16* sm, floatx4 (&acc)[4][4],
                                           int arow, int brow,
                                           int q, int li, int soff, int doff) {
    stage2(a0, b0, sm, soff, doff);   // kt=0 -> buf0
    int cur = 0;
#pragma unroll 1
    for (int kt = 0; kt < KT; ++kt) {
        asm volatile("s_waitcnt vmcnt(0)" ::: "memory");  // own stage(kt) loads landed
        __builtin_amdgcn_s_barrier();                     // all waves' stage(kt) visible
        __builtin_amdgcn_sched_barrier(0);                // nothing crosses above (rule 18)
        if (kt + 1 < KT)
            stage2(a0 + (size_t)(kt + 1) * TILE, b0 + (size_t)(kt + 1) * TILE,
                   sm + (size_t)(cur ^ 1) * 2 * TILE, soff, doff);
        const u16* At = sm + (size_t)(cur * 2 + 0) * TILE;
        const u16* Bt = sm + (size_t)(cur * 2 + 1) * TILE;
        compute_step(At, Bt, arow, brow, acc, q, li);
        __builtin_amdgcn_sched_barrier(0);                // reads can't sink past end barrier
        __builtin_amdgcn_s_barrier();                     // end: all reads of buf[cur] done
        cur ^= 1;
    }
}

// grid = 8 experts x 16 n128-tiles x 9 m-slots = 1152; waves 2x2, 64x64 each
__global__ __launch_bounds__(256) __attribute__((amdgpu_waves_per_eu(2)))
void gemm_a(const u16* __restrict__ At, const u16* __restrict__ Bt,
            const float* __restrict__ bias, u16* __restrict__ hsT,
            const int* __restrict__ cnt, const int* __restrict__ offs) {
    __shared__ u16 sm[2 * 2 * TILE];   // 64 KiB
    int bx = blockIdx.x;
    int e = bx & 7;
    int r = bx >> 3;
    int nt = r & 15;
    int mt0 = r >> 4;
    int count = cnt[e];
    int base128 = offs[e] >> 7;
    int tid = threadIdx.x;
    int w = tid >> 6, l = tid & 63, q = l >> 4, li = l & 15;
    int wm = w >> 1, wn = w & 1;
    int arow = wm * 64, brow = wn * 64;
    int soff = tid * 8, doff = w * 512;
#pragma unroll 1
    for (int mt = mt0; mt * 128 < count; mt += 9) {
        const u16* a0 = At + (size_t)((base128 + mt) * 8) * TILE;
        const u16* b0 = Bt + (size_t)((e * 16 + nt) * 8) * TILE;
        floatx4 acc[4][4];
#pragma unroll
        for (int a = 0; a < 4; ++a)
#pragma unroll
            for (int b = 0; b < 4; ++b) acc[a][b] = (floatx4)0.0f;

        gemm_core2<8>(a0, b0, sm, acc, arow, brow, q, li, soff, doff);

        // epilogue: wave owns 64x64; swizzled image in private 8 KB LDS region
        // (= buf0 slots, last read 2+ barriers ago), dump contiguous.
        float bv[4];
#pragma unroll
        for (int fn = 0; fn < 4; ++fn)
            bv[fn] = bias[(size_t)e * DH + nt * 128 + wn * 64 + fn * 16 + li];
        u16* img = sm + (size_t)w * 4096;
#pragma unroll
        for (int fm = 0; fm < 4; ++fm)
#pragma unroll
            for (int fn = 0; fn < 4; ++fn)
#pragma unroll
                for (int rr = 0; rr < 4; ++rr) {
                    float v = acc[fm][fn][rr] + bv[fn];
                    v = v > 0.0f ? v : 0.0f;
                    int row = fm * 16 + q * 4 + rr;   // 0..63 (wave-local m)
                    int col = fn * 16 + li;           // 0..63 (k-local in hsT tile)
                    img[row * 64 + ((((col >> 3) ^ (row & 7)) << 3) | (col & 7))] = f2bf(v);
                }
        u16* dst = hsT + ((size_t)(base128 + mt) * 32 + nt * 2 + wn) * TILE + wm * 4096;
#pragma unroll
        for (int j = 0; j < 8; ++j)
            *(ushort8*)&dst[j * 512 + l * 8] = *(const ushort8*)&img[j * 512 + l * 8];
        __syncthreads();   // img regions reused as staging buffers next m-iter
    }
}

// ---------------- pass B (FUSED): out[perm[row]] = h @ W2 + b2, full K ----------------
// r10 post-mortem: gemms < 40us each; remaining structural waste = ps round-trip
// (37.7MB write + 33.6MB read + reduce kernel). Fix: full-K gemm_b at 64m x 128n
// (128 thr / 2 waves, KT=32) writing DIRECTLY to out via perm scatter + bias.
// Parallelism kept by halving M-tile: grid = 8e x 4nt x 18 m64-slots = 576.
// LDS = 2 bufs x (A 8KB + B 16KB) = 48KB -> 3 blocks/CU co-resident.
// A-halves of hsT tiles are contiguous 8KB (rows 0-63 / 64-127) -> linear gload.
// K-loop = r10 race-safe schedule verbatim (12 loads/step).
__device__ __forceinline__ void stage_f(const u16* a, const u16* b,
                                        u16* buf, int soff, int doff) {
#pragma unroll
    for (int ch = 0; ch < 4; ++ch)   // A: 4096 elems (8KB)
        __builtin_amdgcn_global_load_lds(GLOBAL_AS(a + ch * 1024 + soff),
                                         LDS_AS(buf + ch * 1024 + doff), 16, 0, 0);
#pragma unroll
    for (int ch = 0; ch < 8; ++ch)   // B: 8192 elems (16KB)
        __builtin_amdgcn_global_load_lds(GLOBAL_AS(b + ch * 1024 + soff),
                                         LDS_AS(buf + 4096 + ch * 1024 + doff), 16, 0, 0);
}

__global__ __launch_bounds__(128) __attribute__((amdgpu_waves_per_eu(2)))
void gemm_b(const u16* __restrict__ At, const u16* __restrict__ Bt,
            const float* __restrict__ b2, const int* __restrict__ perm,
            float* __restrict__ out, const int* __restrict__ cnt,
            const int* __restrict__ offs) {
    __shared__ u16 sm[2 * 12288];   // 48 KiB: per buf {A 4096, B 8192}
    int bx = blockIdx.x;
    int e = bx & 7;
    int r = bx >> 3;
    int nt = r & 3;
    int mt0 = r >> 2;               // 0..17 m64-slots
    int count = cnt[e];
    int seg = offs[e];
    int base128 = seg >> 7;
    int tid = threadIdx.x;
    int w = tid >> 6, l = tid & 63, q = l >> 4, li = l & 15;
    int soff = tid * 8, doff = w * 512;   // 128 thr x 16B = 2KB per gload chunk
    int brow = w * 64;
#pragma unroll 1
    for (int mt = mt0; mt * 64 < count; mt += 18) {
        // A source: 64-row half of hsT 128-row tile (contiguous 8KB)
        const u16* a0 = At + (size_t)((base128 + (mt >> 1)) * 32) * TILE + (mt & 1) * 4096;
        const u16* b0 = Bt + (size_t)((e * 4 + nt) * 32) * TILE;
        floatx4 acc[4][4];
#pragma unroll
        for (int a = 0; a < 4; ++a)
#pragma unroll
            for (int b = 0; b < 4; ++b) acc[a][b] = (floatx4)0.0f;

        // full-K race-safe loop (r10 pattern, 12 gloads/step)
        stage_f(a0, b0, sm, soff, doff);
        int cur = 0;
#pragma unroll 1
        for (int kt = 0; kt < 32; ++kt) {
            asm volatile("s_waitcnt vmcnt(0)" ::: "memory");
            __builtin_amdgcn_s_barrier();
            __builtin_amdgcn_sched_barrier(0);
            if (kt + 1 < 32)
                stage_f(a0 + (size_t)(kt + 1) * TILE, b0 + (size_t)(kt + 1) * TILE,
                        sm + (size_t)(cur ^ 1) * 12288, soff, doff);
            const u16* Atile = sm + (size_t)cur * 12288;
            const u16* Btile = Atile + 4096;
            compute_step(Atile, Btile, 0, brow, acc, q, li);
            __builtin_amdgcn_sched_barrier(0);
            __builtin_amdgcn_s_barrier();
            cur ^= 1;
        }

        // fused epilogue: bias + scatter directly to out via perm (row-guarded).
        // per store instr: 4 rows x 16 consecutive floats = 4 x 64B sectors.
        float bv[4];
#pragma unroll
        for (int fn = 0; fn < 4; ++fn)
            bv[fn] = b2[(size_t)e * DOUT + nt * 128 + brow + fn * 16 + li];
        int rowbase = mt * 64;
#pragma unroll
        for (int fm = 0; fm < 4; ++fm)
#pragma unroll
            for (int rr = 0; rr < 4; ++rr) {
                int lr = fm * 16 + q * 4 + rr;
                if (rowbase + lr < count) {
                    int gi = perm[seg + rowbase + lr];
                    float* orow = out + (size_t)gi * DOUT + nt * 128 + brow;
#pragma unroll
                    for (int fn = 0; fn < 4; ++fn)
                        orow[fn * 16 + li] = acc[fm][fn][rr] + bv[fn];
                }
            }
        __syncthreads();   // LDS safe for next m-iter's prologue stage
    }
}

// ---------------- launch ----------------
extern "C" void kernel_launch(void* const* d_in, const int* in_sizes, int n_in,
                              void* d_out, int out_size, void* d_ws, size_t ws_size,
                              hipStream_t stream) {
    const float* x = (const float*)d_in[0];
    const int* groups = (const int*)d_in[1];
    const float* W1 = (const float*)d_in[2];
    const float* b1 = (const float*)d_in[3];
    const float* W2 = (const float*)d_in[4];
    const float* b2 = (const float*)d_in[5];
    float* out = (float*)d_out;

    char* ws = (char*)d_ws;
    size_t o = 0;
    auto alloc = [&](size_t bytes) {
        void* p = ws + o;
        o = (o + bytes + 255) & ~(size_t)255;
        return p;
    };
    int* cnt = (int*)alloc(NEXP * 4);
    int* offs = (int*)alloc(NEXP * 4);
    int* perm = (int*)alloc((size_t)ROWCAP * 4);
    int* rpos = (int*)alloc((size_t)NB * 4);
    u16* xsT = (u16*)alloc((size_t)(RCAPRD / 128) * 8 * TILE * 2);    // ~10.5 MB
    u16* w1tT = (u16*)alloc((size_t)NEXP * DIN * DH * 2);             // 16.8 MB
    u16* w2tT = (u16*)alloc((size_t)NEXP * DH * DOUT * 2);            // 16.8 MB
    u16* hsT = (u16*)alloc((size_t)(RCAPRD / 128) * 32 * TILE * 2);   // ~41.9 MB

    route_kernel<<<1, 1024, 0, stream>>>(groups, cnt, offs, perm, rpos);
    prep_kernel<<<6144, 256, 0, stream>>>(x, W1, W2, rpos, xsT, w1tT, w2tT);
    gemm_a<<<NEXP * 16 * 9, 256, 0, stream>>>(xsT, w1tT, b1, hsT, cnt, offs);
    gemm_b<<<NEXP * 4 * 18, 128, 0, stream>>>(hsT, w2tT, b2, perm, out, cnt, offs);
}